// Round 6
// baseline (319.672 us; speedup 1.0000x reference)
//
#include <hip/hip_runtime.h>
#include <math.h>

#define NT 4096
#define DP 1024
#define DE 512
#define C0 10000
#define CUT1 30000
#define TAILV 20000
#define WROWS 50240   // 50000 weight rows + zero pad to cover last 256-wide tail tile
#define NBH 40        // head n-blocks (10240/256)
#define NBT 79        // tail n-blocks (20224/256)

typedef unsigned short ushort_t;
typedef short bf8 __attribute__((ext_vector_type(8)));
typedef float f4 __attribute__((ext_vector_type(4)));

__device__ __forceinline__ ushort_t f2b(float f) {
    union { float f; unsigned int u; } v; v.f = f;
    unsigned int r = v.u + 0x7FFFu + ((v.u >> 16) & 1u);
    return (ushort_t)(r >> 16);
}
__device__ __forceinline__ float b2f(ushort_t u) {
    union { unsigned int u; float f; } v; v.u = ((unsigned int)u) << 16; return v.f;
}

__device__ __forceinline__ void gld16(const void* g, void* l) {
    __builtin_amdgcn_global_load_lds(
        (const __attribute__((address_space(1))) unsigned int*)g,
        (__attribute__((address_space(3))) unsigned int*)l, 16, 0, 0);
}

// bijective XCD-chunk swizzle (m204): each XCD owns a contiguous logical chunk
__device__ __forceinline__ int xcd_swz(int wgid, int nwg) {
    int q = nwg >> 3, r = nwg & 7;
    int xcd = wgid & 7, idx = wgid >> 3;
    int base = (xcd < r) ? xcd * (q + 1) : r * (q + 1) + (xcd - r) * q;
    return base + idx;
}

// ---------------- cluster compaction ----------------
__global__ void cluster_kernel(const int* __restrict__ target,
                               int* __restrict__ cnt, int* __restrict__ list) {
    int t = blockIdx.x * blockDim.x + threadIdx.x;
    if (t >= NT) return;
    int tgt = target[t];
    int c = (tgt < C0) ? 0 : (tgt < CUT1 ? 1 : 2);
    if (c > 0) {
        int pos = atomicAdd(&cnt[c - 1], 1);
        list[(c - 1) * NT + pos] = t;
    }
}

// ---------------- fp32 -> bf16 cast (with zero pad region) ----------------
__global__ __launch_bounds__(256)
void cast_pad(const float* __restrict__ in, ushort_t* __restrict__ out,
              int total4, int valid) {
    int i = blockIdx.x * 256 + threadIdx.x;
    if (i >= total4) return;
    int base = i * 4;
    unsigned long long p = 0ull;
    if (base < valid) {
        float4 v = *reinterpret_cast<const float4*>(in + base);
        p = (unsigned long long)f2b(v.x)
          | ((unsigned long long)f2b(v.y) << 16)
          | ((unsigned long long)f2b(v.z) << 32)
          | ((unsigned long long)f2b(v.w) << 48);
    }
    *reinterpret_cast<unsigned long long*>(out + base) = p;
}

// ---------------- projs [3][1024][512] -> bf16 [3][512][1024] (transpose) ----
__global__ __launch_bounds__(256)
void transpose_cast(const float* __restrict__ projs, ushort_t* __restrict__ out) {
    const int cblk = blockIdx.z;
    const int n0 = blockIdx.x * 32;
    const int k0 = blockIdx.y * 32;
    __shared__ float tile[32][33];
    const int tx = threadIdx.x & 31, ty = threadIdx.x >> 5;
    const float* src = projs + (size_t)cblk * DP * DE;
    #pragma unroll
    for (int j = 0; j < 4; ++j)
        tile[ty + j * 8][tx] = src[(size_t)(k0 + ty + j * 8) * DE + n0 + tx];
    __syncthreads();
    ushort_t* dst = out + (size_t)cblk * DE * DP;
    #pragma unroll
    for (int j = 0; j < 4; ++j)
        dst[(size_t)(n0 + ty + j * 8) * DP + k0 + tx] = f2b(tile[tx][ty + j * 8]);
}

// ---------------- MFMA GEMM: C[m][n] = sum_k A[m][k] * B[n][k] ---------------
// 256x256 tile, BK=64, 8 waves (2M x 4N), double-buffered 128KB LDS, 2-phase
// prefetch (stage t+1 into other buffer before computing t; one barrier/tile).
// Flattened 1D grid: logical = xcd_swz(blockIdx.x); mblk = logical & 15.
// MODE 0: proj   (A=hidden_b, B=projsT[c], out: Hb[c] bf16)
// MODE 1: head   (A=Hb[0], B=Wb, epilogue exp-sum -> Ppart[nb][row])
// MODE 2: tail   (A=Hb[1+z] gathered via list, B=Wb+wbase, -> Ppart)
template<int MODE>
__global__ __launch_bounds__(512, 2)
void gemm_bt(const ushort_t* __restrict__ Ab, const ushort_t* __restrict__ Bb,
             ushort_t* __restrict__ Cout, float* __restrict__ Sout,
             const float* __restrict__ bias,
             const int* __restrict__ cnt, const int* __restrict__ list,
             int K, int validN)
{
    const int tid = threadIdx.x;
    const int lane = tid & 63;
    const int w = tid >> 6;            // wave 0..7
    const int wm = w >> 2, wn = w & 3; // 2 M-warps x 4 N-warps

    const int logical = xcd_swz(blockIdx.x, gridDim.x);
    const int bm = (logical & 15) * 256;
    const int bn = (logical >> 4) * 256;
    const int nb = logical >> 4;

    int n = 0;
    if (MODE == 0) {
        Bb += (size_t)blockIdx.z * DE * DP;
        Cout += (size_t)blockIdx.z * (size_t)NT * DE;
    }
    if (MODE == 2) {
        const int tail = blockIdx.z;
        n = cnt[tail];
        if (bm >= n) return;
        Ab += (size_t)(1 + tail) * NT * DE;
        Bb += (size_t)(C0 + tail * TAILV) * DE;
        bias += C0 + tail * TAILV;
        list += tail * NT;
        Sout += (size_t)tail * NBT * NT;
    }

    // 2 buffers x (A 256x128B + B 256x128B) = 2 x 64KB
    __shared__ __align__(16) unsigned char lds[131072];

    // staging: 4 issues x 8 waves x 64 lanes x 16B = 64KB (A+B per issue half).
    // LDS linear [row][128B]; source k-chunk pre-swizzled: chunk = slot^(row&7).
    const int kswz = (lane & 7) ^ (lane >> 3);
    const int dstoff = (w * 8 + (lane >> 3)) * 128 + (lane & 7) * 16;

    const char* ap[4];
    const char* bp[4];
    #pragma unroll
    for (int i = 0; i < 4; ++i) {
        int r = i * 64 + w * 8 + (lane >> 3);   // row in tile 0..255
        int ga;
        if (MODE == 2) {
            int gr = bm + r;
            ga = (gr < n) ? list[gr] : 0;
        } else ga = bm + r;
        ap[i] = (const char*)Ab + (size_t)ga * K * 2 + kswz * 16;
        bp[i] = (const char*)Bb + (size_t)(bn + r) * K * 2 + kswz * 16;
    }

    f4 acc[8][4];
    const f4 zero = {0.f, 0.f, 0.f, 0.f};
    #pragma unroll
    for (int i = 0; i < 8; ++i)
        #pragma unroll
        for (int j = 0; j < 4; ++j) acc[i][j] = zero;

    auto stage = [&](int t, unsigned char* buf) {
        const int kb = t << 7;   // 128 bytes of K per tile
        #pragma unroll
        for (int i = 0; i < 4; ++i) {
            gld16(ap[i] + kb, buf + i * 8192 + dstoff);
            gld16(bp[i] + kb, buf + 32768 + i * 8192 + dstoff);
        }
    };

    const int ntiles = K >> 6;
    stage(0, lds);
    __syncthreads();

    for (int t = 0; t < ntiles; ++t) {
        unsigned char* cur = lds + ((t & 1) ? 65536 : 0);
        if (t + 1 < ntiles)
            stage(t + 1, lds + (((t + 1) & 1) ? 65536 : 0));
        const unsigned char* As = cur;
        const unsigned char* Bs = cur + 32768;
        #pragma unroll
        for (int kh = 0; kh < 2; ++kh) {
            bf8 bv[4];
            #pragma unroll
            for (int nf = 0; nf < 4; ++nf) {
                const int Rb = wn * 64 + nf * 16 + (lane & 15);
                bv[nf] = *reinterpret_cast<const bf8*>(
                    Bs + Rb * 128 + (((kh * 4 + (lane >> 4)) ^ (Rb & 7)) << 4));
            }
            #pragma unroll
            for (int mf = 0; mf < 8; ++mf) {
                const int Ra = wm * 128 + mf * 16 + (lane & 15);
                bf8 af = *reinterpret_cast<const bf8*>(
                    As + Ra * 128 + (((kh * 4 + (lane >> 4)) ^ (Ra & 7)) << 4));
                #pragma unroll
                for (int nf = 0; nf < 4; ++nf)
                    acc[mf][nf] = __builtin_amdgcn_mfma_f32_16x16x32_bf16(
                        af, bv[nf], acc[mf][nf], 0, 0, 0);
            }
        }
        __syncthreads();   // drains stage(t+1) vmcnt + protects buffer reuse
    }

    if (MODE == 0) {
        #pragma unroll
        for (int mf = 0; mf < 8; ++mf) {
            const int row = bm + wm * 128 + mf * 16 + ((lane >> 4) << 2);
            #pragma unroll
            for (int nf = 0; nf < 4; ++nf) {
                const int col = bn + wn * 64 + nf * 16 + (lane & 15);
                #pragma unroll
                for (int r = 0; r < 4; ++r)
                    Cout[(size_t)(row + r) * DE + col] = f2b(acc[mf][nf][r]);
            }
        }
    } else {
        float rs[8][4];
        #pragma unroll
        for (int mf = 0; mf < 8; ++mf)
            #pragma unroll
            for (int r = 0; r < 4; ++r) {
                float s = 0.f;
                #pragma unroll
                for (int nf = 0; nf < 4; ++nf) {
                    const int col = bn + wn * 64 + nf * 16 + (lane & 15);
                    if (col < validN) s += __expf(acc[mf][nf][r] + bias[col]);
                }
                rs[mf][r] = s;
            }
        #pragma unroll
        for (int m = 1; m < 16; m <<= 1)
            #pragma unroll
            for (int mf = 0; mf < 8; ++mf)
                #pragma unroll
                for (int r = 0; r < 4; ++r)
                    rs[mf][r] += __shfl_xor(rs[mf][r], m);
        // cross-wave combine in LDS (reuse staging buffer), then plain store
        float* ps = (float*)lds;     // ps[wn][256] rows
        if ((lane & 15) == 0) {
            const int rb = (lane >> 4) << 2;
            #pragma unroll
            for (int mf = 0; mf < 8; ++mf)
                #pragma unroll
                for (int r = 0; r < 4; ++r)
                    ps[wn * 256 + wm * 128 + mf * 16 + rb + r] = rs[mf][r];
        }
        __syncthreads();
        if (tid < 256) {
            float v = ps[tid] + ps[256 + tid] + ps[512 + tid] + ps[768 + tid];
            Sout[(size_t)nb * NT + bm + tid] = v;   // partial; garbage rows unread
        }
    }
}

// ---------------- partial reduce: S = sum over n-blocks (no atomics) ---------
__global__ __launch_bounds__(256)
void reduce_kernel(const float* __restrict__ Ph, const float* __restrict__ Pt,
                   const int* __restrict__ cnt, const int* __restrict__ list,
                   float* __restrict__ S_head, float* __restrict__ S_tail) {
    const int z = blockIdx.y;
    const int t = blockIdx.x * 256 + threadIdx.x;
    if (z == 0) {
        if (t >= NT) return;
        float s = 0.f;
        for (int nb = 0; nb < NBH; ++nb) s += Ph[(size_t)nb * NT + t];
        S_head[t] = s;
    } else {
        const int tail = z - 1;
        if (t >= cnt[tail]) return;
        const float* P = Pt + (size_t)tail * NBT * NT;
        float s = 0.f;
        for (int nb = 0; nb < NBT; ++nb) s += P[(size_t)nb * NT + t];
        S_tail[list[tail * NT + t]] = s;
    }
}

// ---------------- finalize: cluster logits + target logit + NLL --------------
__global__ __launch_bounds__(64)
void finalize_kernel(const ushort_t* __restrict__ Hb, const int* __restrict__ target,
                     const float* __restrict__ weight, const float* __restrict__ bias,
                     const float* __restrict__ cw, const float* __restrict__ cb,
                     const float* __restrict__ S_head, const float* __restrict__ S_tail,
                     float* __restrict__ out)
{
    const int t = blockIdx.x, lane = threadIdx.x;
    const int tgt = target[t];
    const int c = (tgt < C0) ? 0 : (tgt < CUT1 ? 1 : 2);
    const int e = lane * 8;

    union { uint4 u; ushort_t s[8]; } h0;
    h0.u = *reinterpret_cast<const uint4*>(Hb + (size_t)t * DE + e);
    float hv[8];
    #pragma unroll
    for (int k = 0; k < 8; ++k) hv[k] = b2f(h0.s[k]);

    float c1 = 0.f, c2 = 0.f;
    #pragma unroll
    for (int k = 0; k < 8; ++k) {
        c1 += hv[k] * cw[e + k];
        c2 += hv[k] * cw[DE + e + k];
    }

    const ushort_t* hs = (c == 0) ? (Hb + (size_t)t * DE)
                                  : (Hb + ((size_t)c * NT + (size_t)t) * DE);
    union { uint4 u; ushort_t s[8]; } hc;
    hc.u = *reinterpret_cast<const uint4*>(hs + e);
    const float* wt = weight + (size_t)tgt * DE;
    float dt = 0.f;
    #pragma unroll
    for (int k = 0; k < 8; ++k) dt += b2f(hc.s[k]) * wt[e + k];

    #pragma unroll
    for (int m = 32; m; m >>= 1) {
        c1 += __shfl_xor(c1, m);
        c2 += __shfl_xor(c2, m);
        dt += __shfl_xor(dt, m);
    }
    if (lane == 0) {
        c1 += cb[0]; c2 += cb[1];
        const float S = S_head[t] + __expf(c1) + __expf(c2);
        const float lsh = logf(S);
        float res;
        if (c == 0) {
            res = lsh - (dt + bias[tgt]);
        } else {
            const float cl = (c == 1) ? c1 : c2;
            res = (lsh - cl) + (logf(S_tail[t]) - (dt + bias[tgt]));
        }
        out[t] = res;
    }
}

extern "C" void kernel_launch(void* const* d_in, const int* in_sizes, int n_in,
                              void* d_out, int out_size, void* d_ws, size_t ws_size,
                              hipStream_t stream) {
    const float* hidden = (const float*)d_in[0];
    const int*   target = (const int*)d_in[1];
    const float* weight = (const float*)d_in[2];
    const float* bias   = (const float*)d_in[3];
    const float* cw     = (const float*)d_in[4];
    const float* cb     = (const float*)d_in[5];
    const float* projs  = (const float*)d_in[6];
    float* out = (float*)d_out;

    char* w = (char*)d_ws;
    ushort_t* Hb      = (ushort_t*)w;  w += (size_t)3 * NT * DE * 2;
    ushort_t* hiddenb = (ushort_t*)w;  w += (size_t)NT * DP * 2;
    ushort_t* Wb      = (ushort_t*)w;  w += (size_t)WROWS * DE * 2;
    ushort_t* projsTb = (ushort_t*)w;  w += (size_t)3 * DE * DP * 2;
    float* S_head = (float*)w;         w += NT * 4;
    float* S_tail = (float*)w;         w += NT * 4;
    int* cnt      = (int*)w;           w += 32;
    int* list     = (int*)w;           w += 2 * NT * 4;
    float* Ph     = (float*)w;         w += (size_t)NBH * NT * 4;
    float* Pt     = (float*)w;         w += (size_t)2 * NBT * NT * 4;

    hipMemsetAsync(cnt, 0, 32, stream);
    cluster_kernel<<<NT / 256, 256, 0, stream>>>(target, cnt, list);
    cast_pad<<<(NT * DP / 4 + 255) / 256, 256, 0, stream>>>(
        hidden, hiddenb, NT * DP / 4, NT * DP);
    cast_pad<<<(WROWS * DE / 4 + 255) / 256, 256, 0, stream>>>(
        weight, Wb, WROWS * DE / 4, 50000 * DE);
    transpose_cast<<<dim3(DE / 32, DP / 32, 3), 256, 0, stream>>>(projs, projsTb);

    // grids: x = MB(16) * NB, mblk fastest (B-tile reuse within XCD chunk)
    gemm_bt<0><<<dim3(16 * 2, 1, 3), 512, 0, stream>>>(
        hiddenb, projsTb, Hb, nullptr, nullptr, nullptr, nullptr, DP, DE);
    gemm_bt<1><<<dim3(16 * NBH, 1, 1), 512, 0, stream>>>(
        Hb, Wb, nullptr, Ph, bias, nullptr, nullptr, DE, C0);
    gemm_bt<2><<<dim3(16 * NBT, 1, 2), 512, 0, stream>>>(
        Hb, Wb, nullptr, Pt, bias, cnt, list, DE, TAILV);
    reduce_kernel<<<dim3(NT / 256, 3), 256, 0, stream>>>(
        Ph, Pt, cnt, list, S_head, S_tail);
    finalize_kernel<<<NT, 64, 0, stream>>>(
        Hb, target, weight, bias, cw, cb, S_head, S_tail, out);
}